// Round 1
// baseline (411.444 us; speedup 1.0000x reference)
//
#include <hip/hip_runtime.h>
#include <cmath>

#define HH 512
#define WW 512
#define NIMG 64
#define OHH 502
#define OWW 502
#define TS 32

struct KTaps {
    float kw[11];   // normalized gaussian, win=11, sigma=1.5
    float ke[13];   // erf-gaussian, 13 taps, NOT normalized
};

// ---------------- Kernel A: SSIM map -> scalar sum ----------------
__global__ __launch_bounds__(256) void ssim_reduce_kernel(
        const float* __restrict__ x, const float* __restrict__ y,
        double* __restrict__ ssum, KTaps kt) {
    __shared__ float sx[42][42];
    __shared__ float sy[42][42];
    __shared__ float hx[42][32];
    __shared__ float hy[42][32];
    __shared__ float hxx[42][32];
    __shared__ float hyy[42][32];
    __shared__ float hxy[42][32];

    const int n  = blockIdx.z;
    const int bi = blockIdx.y * TS;   // output-row base == input-row base (valid conv)
    const int bj = blockIdx.x * TS;
    const int tid = threadIdx.x;

    const float* __restrict__ xi = x + (size_t)n * HH * WW;
    const float* __restrict__ yi = y + (size_t)n * HH * WW;

    // load 42x42 halo region (bounds-checked; OOB values feed masked outputs only)
    for (int idx = tid; idx < 42 * 42; idx += 256) {
        const int r = idx / 42, c = idx % 42;
        const int gr = bi + r, gc = bj + c;
        float xv = 0.f, yv = 0.f;
        if (gr < HH && gc < WW) {
            xv = xi[gr * WW + gc];
            yv = yi[gr * WW + gc];
        }
        sx[r][c] = xv;
        sy[r][c] = yv;
    }
    __syncthreads();

    // horizontal pass: 5 filtered quantities at 42 rows x 32 output cols
    for (int idx = tid; idx < 42 * 32; idx += 256) {
        const int r = idx / 32, c = idx % 32;
        float ax = 0.f, ay = 0.f, axx = 0.f, ayy = 0.f, axy = 0.f;
#pragma unroll
        for (int v = 0; v < 11; ++v) {
            const float w  = kt.kw[v];
            const float xv = sx[r][c + v];
            const float yv = sy[r][c + v];
            ax  += w * xv;
            ay  += w * yv;
            axx += w * xv * xv;
            ayy += w * yv * yv;
            axy += w * xv * yv;
        }
        hx[r][c] = ax;  hy[r][c] = ay;
        hxx[r][c] = axx; hyy[r][c] = ayy; hxy[r][c] = axy;
    }
    __syncthreads();

    const float c1 = 1e-4f;   // (0.01*1)^2
    const float c2 = 9e-4f;   // (0.03*1)^2
    float acc = 0.f;

    // vertical pass + ssim formula + masked accumulate
    for (int idx = tid; idx < 32 * 32; idx += 256) {
        const int r = idx / 32, c = idx % 32;
        const int go_i = bi + r, go_j = bj + c;
        if (go_i < OHH && go_j < OWW) {
            float mx = 0.f, my = 0.f, mxx = 0.f, myy = 0.f, mxy = 0.f;
#pragma unroll
            for (int u = 0; u < 11; ++u) {
                const float w = kt.kw[u];
                mx  += w * hx[r + u][c];
                my  += w * hy[r + u][c];
                mxx += w * hxx[r + u][c];
                myy += w * hyy[r + u][c];
                mxy += w * hxy[r + u][c];
            }
            const float vx  = mxx - mx * mx;
            const float vy  = myy - my * my;
            const float cov = mxy - mx * my;
            const float ssim = ((2.f * mx * my + c1) * (2.f * cov + c2)) /
                               ((mx * mx + my * my + c1) * (vx + vy + c2));
            acc += ssim;
        }
    }

    // wave (64-lane) shuffle reduce, then cross-wave via LDS, one atomic/block
#pragma unroll
    for (int off = 32; off > 0; off >>= 1)
        acc += __shfl_down(acc, off, 64);
    __shared__ float wsum[4];
    const int wid = tid >> 6, lane = tid & 63;
    if (lane == 0) wsum[wid] = acc;
    __syncthreads();
    if (tid == 0) {
        const float s = wsum[0] + wsum[1] + wsum[2] + wsum[3];
        atomicAdd(ssum, (double)s);
    }
}

// ---------------- Kernel B: L1 map + combine with ssim scalar ----------------
__global__ __launch_bounds__(256) void l1_combine_kernel(
        const float* __restrict__ x, const float* __restrict__ y,
        const double* __restrict__ ssum, float* __restrict__ out, KTaps kt) {
    __shared__ float sd[44][44];
    __shared__ float hd[44][32];

    const int n  = blockIdx.z;
    const int bi = blockIdx.y * TS;
    const int bj = blockIdx.x * TS;
    const int tid = threadIdx.x;

    const float* __restrict__ xi = x + (size_t)n * HH * WW;
    const float* __restrict__ yi = y + (size_t)n * HH * WW;

    // load 44x44 halo of d = y - x with zero padding (SAME conv, pad=6)
    for (int idx = tid; idx < 44 * 44; idx += 256) {
        const int r = idx / 44, c = idx % 44;
        const int gr = bi + r - 6, gc = bj + c - 6;
        float v = 0.f;
        if (gr >= 0 && gr < HH && gc >= 0 && gc < WW)
            v = yi[gr * WW + gc] - xi[gr * WW + gc];
        sd[r][c] = v;
    }
    __syncthreads();

    // horizontal 13-tap pass
    for (int idx = tid; idx < 44 * 32; idx += 256) {
        const int r = idx / 32, c = idx % 32;
        float a = 0.f;
#pragma unroll
        for (int v = 0; v < 13; ++v) a += kt.ke[v] * sd[r][c + v];
        hd[r][c] = a;
    }
    __syncthreads();

    const float inv_cnt = 1.f / 16128256.f;   // 64*502*502
    const float ssim_loss = 1.f - (float)(*ssum) * inv_cnt;
    const float base = 100.f * 0.84f * ssim_loss;

    float* __restrict__ oi = out + (size_t)n * HH * WW;
    for (int idx = tid; idx < 32 * 32; idx += 256) {
        const int r = idx / 32, c = idx % 32;
        float a = 0.f;
#pragma unroll
        for (int u = 0; u < 13; ++u) a += kt.ke[u] * hd[r + u][c];
        oi[(size_t)(bi + r) * WW + (bj + c)] = base + 100.f * 0.16f * fabsf(a);
    }
}

extern "C" void kernel_launch(void* const* d_in, const int* in_sizes, int n_in,
                              void* d_out, int out_size, void* d_ws, size_t ws_size,
                              hipStream_t stream) {
    const float* x = (const float*)d_in[0];
    const float* y = (const float*)d_in[1];
    float* out = (float*)d_out;
    double* ssum = (double*)d_ws;

    KTaps kt;
    {   // normalized gaussian win=11 sigma=1.5 (exp-based)
        double g[11], s = 0.0;
        for (int i = 0; i < 11; ++i) {
            const double d = (double)i - 5.0;
            g[i] = std::exp(-(d * d) / 4.5);
            s += g[i];
        }
        for (int i = 0; i < 11; ++i) kt.kw[i] = (float)(g[i] / s);
    }
    {   // erf-gaussian, tail=6 -> 13 taps, sigma=1.5, NOT normalized
        const double t = 0.70710678 / 1.5;
        for (int i = 0; i < 13; ++i) {
            const double xx = (double)i - 6.0;
            const double v = 0.5 * (std::erf(t * (xx + 0.5)) - std::erf(t * (xx - 0.5)));
            kt.ke[i] = (float)(v < 0.0 ? 0.0 : v);
        }
    }

    hipMemsetAsync(ssum, 0, sizeof(double), stream);

    dim3 blk(256);
    dim3 grdA((OWW + TS - 1) / TS, (OHH + TS - 1) / TS, NIMG);   // 16x16x64
    ssim_reduce_kernel<<<grdA, blk, 0, stream>>>(x, y, ssum, kt);

    dim3 grdB(WW / TS, HH / TS, NIMG);                           // 16x16x64
    l1_combine_kernel<<<grdB, blk, 0, stream>>>(x, y, ssum, out, kt);
}